// Round 14
// baseline (45.856 us; speedup 1.0000x reference)
//
#include <hip/hip_runtime.h>
#include <hip/hip_fp16.h>

#define DIM 128
#define GROWS 32

typedef _Float16 f16x8 __attribute__((ext_vector_type(8)));
typedef float f32x4 __attribute__((ext_vector_type(4)));

// ---------- Kernel 1 (fused): qtab = int8 TILE-quant(emb @ W),
// scales16[mt] = max|tile|/127 over each 16-row vocab tile, via fp16 MFMA
// + segment-boundary scan in the same launch. r13-exact (best measured).
// Failed alternatives (measured): LDS W-staging r5 +10us / r8 +3.4us;
// split-N waves r10 +5us; single-address atomicMax r4 +30us; st-stream
// r6 +5us; NT row loads r12 +9.3us. Do not revisit.
//
// MFMA fragment layouts (mfma_f32_16x16x32_f16, harness-verified round 1):
//   A (16x32): row = lane&15, k = (lane>>4)*8 + i  -> 8 contiguous floats
//   B (32x16): col = lane&15, k = (lane>>4)*8 + i  -> stride-DIM scalars
//   D (16x16): col = lane&15, row = (lane>>4)*4 + reg
__global__ __launch_bounds__(256, 2) void prep_kernel(
    const int* __restrict__ segs, int* __restrict__ seg_start,
    const float* __restrict__ emb, const float* __restrict__ W,
    signed char* __restrict__ qtab, float* __restrict__ scales16,
    int T, int B, int V, int mtiles, int nTrans) {
  if ((int)blockIdx.x >= nTrans) {
    // ---- boundaries: seg_start[s] = lower_bound(segs, s), streaming ----
    const int i = (blockIdx.x - nTrans) * 256 + threadIdx.x;
    if (i > T) return;
    const int cur = (i < T) ? segs[i] : B;
    const int prev = (i > 0) ? segs[i - 1] : -1;
    for (int s = prev + 1; s <= cur; ++s) seg_start[s] = i;
    return;
  }

  const int wid = blockIdx.x * 4 + (threadIdx.x >> 6);
  const int nwaves = nTrans * 4;
  const int lane = threadIdx.x & 63;
  const int lr = lane & 15;   // A-row / B-col / D-col
  const int lg = lane >> 4;   // k-group (A/B), row-group (D)

  // Preload all B fragments of W (fp32 -> fp16). W is 64KB, L1/L2-hot.
  f16x8 bfrag[8][4];
#pragma unroll
  for (int n = 0; n < 8; ++n)
#pragma unroll
    for (int s = 0; s < 4; ++s) {
      const float* wp = W + (size_t)(s * 32 + lg * 8) * DIM + n * 16 + lr;
      f16x8 f;
#pragma unroll
      for (int i = 0; i < 8; ++i) f[i] = (_Float16)wp[(size_t)i * DIM];
      bfrag[n][s] = f;
    }

  for (int mt = wid; mt < mtiles; mt += nwaves) {
    const float* arow = emb + (size_t)(mt * 16 + lr) * DIM;
    f16x8 afrag[4];
#pragma unroll
    for (int s = 0; s < 4; ++s) {
      const float4 a0 = *reinterpret_cast<const float4*>(arow + s * 32 + lg * 8);
      const float4 a1 = *reinterpret_cast<const float4*>(arow + s * 32 + lg * 8 + 4);
      f16x8 f;
      f[0] = (_Float16)a0.x; f[1] = (_Float16)a0.y;
      f[2] = (_Float16)a0.z; f[3] = (_Float16)a0.w;
      f[4] = (_Float16)a1.x; f[5] = (_Float16)a1.y;
      f[6] = (_Float16)a1.z; f[7] = (_Float16)a1.w;
      afrag[s] = f;
    }
    f32x4 accs[8];
#pragma unroll
    for (int n = 0; n < 8; ++n) {
      f32x4 a = {0.f, 0.f, 0.f, 0.f};
#pragma unroll
      for (int s = 0; s < 4; ++s)
        a = __builtin_amdgcn_mfma_f32_16x16x32_f16(afrag[s], bfrag[n][s],
                                                   a, 0, 0, 0);
      accs[n] = a;
    }
    // tile absmax: in-lane over n and j, then across all 64 lanes
    const int r0 = mt * 16 + lg * 4;
    float tm = 0.f;
#pragma unroll
    for (int j = 0; j < 4; ++j) {
      float m = fabsf(accs[0][j]);
#pragma unroll
      for (int n = 1; n < 8; ++n) m = fmaxf(m, fabsf(accs[n][j]));
      tm = fmaxf(tm, m);
    }
    tm = fmaxf(tm, __shfl_xor(tm, 1));
    tm = fmaxf(tm, __shfl_xor(tm, 2));
    tm = fmaxf(tm, __shfl_xor(tm, 4));
    tm = fmaxf(tm, __shfl_xor(tm, 8));
    tm = fmaxf(tm, __shfl_xor(tm, 16));
    tm = fmaxf(tm, __shfl_xor(tm, 32));
    const float inv = (tm > 0.f) ? 127.f / tm : 0.f;
    if (lane == 0) scales16[mt] = tm * (1.f / 127.f);
#pragma unroll
    for (int n = 0; n < 8; ++n)
#pragma unroll
      for (int j = 0; j < 4; ++j)
        qtab[(size_t)(r0 + j) * DIM + n * 16 + lr] =
            (signed char)(int)rintf(accs[n][j] * inv);
  }

  // tail rows if V % 16 != 0 (dead for V=100000, kept for safety)
  const int tailStart = mtiles * 16;
  if (wid == 0 && tailStart < V) {
    const int c2 = lane * 2;
    float tmax = 0.f;
    for (int r = tailStart; r < V; ++r) {
      float s0 = 0.f, s1 = 0.f;
      for (int k = 0; k < DIM; ++k) {
        const float e = emb[(size_t)r * DIM + k];
        s0 = fmaf(e, W[(size_t)k * DIM + c2], s0);
        s1 = fmaf(e, W[(size_t)k * DIM + c2 + 1], s1);
      }
      float mm = fmaxf(fabsf(s0), fabsf(s1));
      mm = fmaxf(mm, __shfl_xor(mm, 1));
      mm = fmaxf(mm, __shfl_xor(mm, 2));
      mm = fmaxf(mm, __shfl_xor(mm, 4));
      mm = fmaxf(mm, __shfl_xor(mm, 8));
      mm = fmaxf(mm, __shfl_xor(mm, 16));
      mm = fmaxf(mm, __shfl_xor(mm, 32));
      tmax = fmaxf(tmax, mm);
    }
    if (lane == 0) scales16[tailStart >> 4] = tmax * (1.f / 127.f);
    const float iv = (tmax > 0.f) ? 127.f / tmax : 0.f;
    for (int r = tailStart; r < V; ++r) {
      float s0 = 0.f, s1 = 0.f;
      for (int k = 0; k < DIM; ++k) {
        const float e = emb[(size_t)r * DIM + k];
        s0 = fmaf(e, W[(size_t)k * DIM + c2], s0);
        s1 = fmaf(e, W[(size_t)k * DIM + c2 + 1], s1);
      }
      qtab[(size_t)r * DIM + c2] = (signed char)(int)rintf(s0 * iv);
      qtab[(size_t)r * DIM + c2 + 1] = (signed char)(int)rintf(s1 * iv);
    }
  }
}

// ---------- Kernel 2: int8 gather + segment sum + bias + relu -------------
// Round-14: 32-waves/CU occupancy. r4's segsum (the only one to beat
// 28us: ~21us) ran at (256,8); r7/r13 ran at (256,4)=16 waves/CU. In the
// latency-bound gather regime, resident-wave count is the MLP multiplier.
// To fit the 64-VGPR budget WITHOUT the r3 serialization trap, the true
// register need is cut to ~55: uint2 row loads (16 lanes x 8B = one 128B
// row per lane-quad, 4 rows/instruction), 32-row clamped batches, acc[8].
// Tile scales (25KB, L2-hot) as r13. Phase-split token -> scale+row ->
// fma as r7.

#define ACC4(w, o, SV)                                                     \
  acc[(o) + 0] = fmaf(SV, (float)((int)((w) << 24) >> 24), acc[(o) + 0]);  \
  acc[(o) + 1] = fmaf(SV, (float)((int)((w) << 16) >> 24), acc[(o) + 1]);  \
  acc[(o) + 2] = fmaf(SV, (float)((int)((w) <<  8) >> 24), acc[(o) + 2]);  \
  acc[(o) + 3] = fmaf(SV, (float)((int)(w) >> 24),         acc[(o) + 3]);

__global__ __launch_bounds__(256, 8) void segsum_q8(
    const int* __restrict__ tokens, const signed char* __restrict__ qtab,
    const float* __restrict__ scales16, const int* __restrict__ seg_start,
    const float* __restrict__ bias, float* __restrict__ out, int B) {
  const int seg = blockIdx.x * 4 + (threadIdx.x >> 6);
  if (seg >= B) return;
  const int lane = threadIdx.x & 63;
  const int g = lane >> 4;            // row-in-quad 0..3
  const int c8 = (lane & 15) * 8;     // byte offset of this lane's 8 dims
  const int lo = seg_start[seg], hi = seg_start[seg + 1];
  const int cnt = hi - lo;
  const int last = hi - 1;
  float acc[8] = {0.f, 0.f, 0.f, 0.f, 0.f, 0.f, 0.f, 0.f};

  const int nbatch = (cnt + 31) >> 5;
  for (int b = 0; b < nbatch; ++b) {
    const int base = lo + (b << 5);
    // phase 1: token loads (streamed, L1-hot)
    int tok[8];
    float sv[8];
#pragma unroll
    for (int u = 0; u < 8; ++u) {
      const int idx = base + 4 * u + g;
      tok[u] = tokens[min(idx, last)];
      sv[u] = (idx <= last) ? 0.f : -1.f;  // marker; replaced in phase 2
    }
    // phase 2: 8 tile-scale loads (25KB, L2-hot) + 8 random 128B row loads
    uint2 rv[8];
#pragma unroll
    for (int u = 0; u < 8; ++u) {
      sv[u] = (sv[u] == 0.f) ? scales16[tok[u] >> 4] : 0.f;
      rv[u] = *reinterpret_cast<const uint2*>(
          qtab + (size_t)tok[u] * DIM + c8);
    }
    // phase 3: decode + accumulate (masked rows have sv=0)
#pragma unroll
    for (int u = 0; u < 8; ++u) {
      ACC4(rv[u].x, 0, sv[u])
      ACC4(rv[u].y, 4, sv[u])
    }
  }
#pragma unroll
  for (int i = 0; i < 8; ++i) {
    acc[i] += __shfl_xor(acc[i], 16);
    acc[i] += __shfl_xor(acc[i], 32);
  }
  if (g == 0) {
    float* op = out + (size_t)seg * DIM + c8;
    const float* bp = bias + c8;
#pragma unroll
    for (int j = 0; j < 2; ++j) {
      const float4 bv = *reinterpret_cast<const float4*>(bp + 4 * j);
      float4 o;
      o.x = fmaxf(acc[4 * j + 0] + bv.x, 0.f);
      o.y = fmaxf(acc[4 * j + 1] + bv.y, 0.f);
      o.z = fmaxf(acc[4 * j + 2] + bv.z, 0.f);
      o.w = fmaxf(acc[4 * j + 3] + bv.w, 0.f);
      *reinterpret_cast<float4*>(op + 4 * j) = o;
    }
  }
}
#undef ACC4

// =================== fp32 fallback path (ws too small) ====================
__global__ __launch_bounds__(256) void boundaries_kernel(
    const int* __restrict__ segs, int* __restrict__ seg_start, int T, int B) {
  const int i = blockIdx.x * 256 + threadIdx.x;
  if (i > T) return;
  const int cur = (i < T) ? segs[i] : B;
  const int prev = (i > 0) ? segs[i - 1] : -1;
  for (int s = prev + 1; s <= cur; ++s) seg_start[s] = i;
}

#define LOADF(u, TIDX)                                                     \
  const int t##u = tokens[(TIDX)];                                         \
  const float4 e##u = *reinterpret_cast<const float4*>(                    \
      emb + (size_t)t##u * DIM + c4);
#define ADDF(u) { acc.x += e##u.x; acc.y += e##u.y; acc.z += e##u.z; acc.w += e##u.w; }

__global__ __launch_bounds__(256, 4) void segsum_f32(
    const int* __restrict__ tokens, const float* __restrict__ emb,
    const int* __restrict__ seg_start, float* __restrict__ bow, int B) {
  const int seg = blockIdx.x * 4 + (threadIdx.x >> 6);
  if (seg >= B) return;
  const int lane = threadIdx.x & 63;
  const int half = lane >> 5;
  const int c4 = (lane & 31) * 4;
  const int lo = seg_start[seg], hi = seg_start[seg + 1];
  const int cnt = hi - lo;
  float4 acc = make_float4(0.f, 0.f, 0.f, 0.f);

  int base = lo;
  const int nb = cnt >> 4;
  for (int b = 0; b < nb; ++b, base += 16) {
    LOADF(0, base + 0 + half)  LOADF(1, base + 2 + half)
    LOADF(2, base + 4 + half)  LOADF(3, base + 6 + half)
    LOADF(4, base + 8 + half)  LOADF(5, base + 10 + half)
    LOADF(6, base + 12 + half) LOADF(7, base + 14 + half)
    ADDF(0) ADDF(1) ADDF(2) ADDF(3) ADDF(4) ADDF(5) ADDF(6) ADDF(7)
  }
  if (cnt & 15) {
    const int last = hi - 1;
#define LOADT(u) const int i##u = base + 2 * u + half; LOADF(u, min(i##u, last))
    LOADT(0) LOADT(1) LOADT(2) LOADT(3)
    LOADT(4) LOADT(5) LOADT(6) LOADT(7)
    if (i0 <= last) ADDF(0)
    if (i1 <= last) ADDF(1)
    if (i2 <= last) ADDF(2)
    if (i3 <= last) ADDF(3)
    if (i4 <= last) ADDF(4)
    if (i5 <= last) ADDF(5)
    if (i6 <= last) ADDF(6)
    if (i7 <= last) ADDF(7)
#undef LOADT
  }
  acc.x += __shfl_xor(acc.x, 32);
  acc.y += __shfl_xor(acc.y, 32);
  acc.z += __shfl_xor(acc.z, 32);
  acc.w += __shfl_xor(acc.w, 32);
  if (half == 0)
    *reinterpret_cast<float4*>(bow + (size_t)seg * DIM + c4) = acc;
}

// out = relu(bow @ W + b), in-place over d_out (fallback only)
__global__ __launch_bounds__(256) void gemm_bias_relu(
    const float* __restrict__ bow, const float* __restrict__ W,
    const float* __restrict__ bias, float* __restrict__ out) {
  __shared__ float bt[GROWS][DIM];
  const int tid = threadIdx.x;
  const size_t row0 = (size_t)blockIdx.x * GROWS;

  {
    const float4* src = reinterpret_cast<const float4*>(bow + row0 * DIM);
    float4* dst = reinterpret_cast<float4*>(&bt[0][0]);
#pragma unroll
    for (int i = 0; i < (GROWS * DIM / 4) / 256; ++i)
      dst[tid + 256 * i] = src[tid + 256 * i];
  }
  __syncthreads();

  const int cg = tid & 31;
  const int rg = tid >> 5;
  const int c0 = cg * 4;

  float acc[4][4] = {};
#pragma unroll 4
  for (int k = 0; k < DIM; ++k) {
    const float4 w4 = *reinterpret_cast<const float4*>(W + (size_t)k * DIM + c0);
#pragma unroll
    for (int j = 0; j < 4; ++j) {
      const float s = bt[rg * 4 + j][k];
      acc[j][0] = fmaf(s, w4.x, acc[j][0]);
      acc[j][1] = fmaf(s, w4.y, acc[j][1]);
      acc[j][2] = fmaf(s, w4.z, acc[j][2]);
      acc[j][3] = fmaf(s, w4.w, acc[j][3]);
    }
  }

  const float4 bv = *reinterpret_cast<const float4*>(bias + c0);
#pragma unroll
  for (int j = 0; j < 4; ++j) {
    float4 o;
    o.x = fmaxf(acc[j][0] + bv.x, 0.f);
    o.y = fmaxf(acc[j][1] + bv.y, 0.f);
    o.z = fmaxf(acc[j][2] + bv.z, 0.f);
    o.w = fmaxf(acc[j][3] + bv.w, 0.f);
    *reinterpret_cast<float4*>(out + (row0 + rg * 4 + j) * DIM + c0) = o;
  }
}

extern "C" void kernel_launch(void* const* d_in, const int* in_sizes, int n_in,
                              void* d_out, int out_size, void* d_ws, size_t ws_size,
                              hipStream_t stream) {
  const int* tokens = (const int*)d_in[0];
  const int* segs = (const int*)d_in[1];
  const float* emb = (const float*)d_in[2];
  const float* W = (const float*)d_in[3];
  const float* bias = (const float*)d_in[4];
  float* out = (float*)d_out;

  const int T = in_sizes[0];
  const int B = out_size / DIM;       // 16384
  const int V = in_sizes[2] / DIM;    // 100000

  int* seg_start = (int*)d_ws;                       // (B+1) ints
  const size_t ss_bytes = ((size_t)(B + 1) * 4 + 255) & ~(size_t)255;
  const size_t sc_bytes = (((size_t)(V + 15) / 16) * 4 + 255) & ~(size_t)255;

  const bool qok = ws_size >= ss_bytes + sc_bytes + (size_t)V * DIM;
  if (qok) {
    float* scales16 = (float*)((char*)d_ws + ss_bytes);
    signed char* qtab = (signed char*)((char*)d_ws + ss_bytes + sc_bytes);
    const int nbBound = (T + 1 + 255) / 256;
    const int NTRANS = 512;                          // 2 blocks/CU, 1 generation
    const int mtiles = V / 16;
    prep_kernel<<<NTRANS + nbBound, 256, 0, stream>>>(
        segs, seg_start, emb, W, qtab, scales16, T, B, V, mtiles, NTRANS);
    segsum_q8<<<(B + 3) / 4, 256, 0, stream>>>(
        tokens, qtab, scales16, seg_start, bias, out, B);
  } else {
    float* bow = out;                                // in-place: gather -> GEMM
    boundaries_kernel<<<(T + 1 + 255) / 256, 256, 0, stream>>>(segs, seg_start, T, B);
    segsum_f32<<<(B + 3) / 4, 256, 0, stream>>>(tokens, emb, seg_start, bow, B);
    gemm_bias_relu<<<B / GROWS, 256, 0, stream>>>(bow, W, bias, out);
  }
}

// Round 15
// 44.941 us; speedup vs baseline: 1.0204x; 1.0204x over previous
//
#include <hip/hip_runtime.h>
#include <hip/hip_fp16.h>

#define DIM 128
#define GROWS 32

typedef _Float16 f16x8 __attribute__((ext_vector_type(8)));
typedef float f32x4 __attribute__((ext_vector_type(4)));

// ---------- Kernel 1 (fused): qtab = int8 TILE-quant(emb @ W),
// scales16[mt] = max|tile|/127 over each 16-row vocab tile, via fp16 MFMA
// + segment-boundary scan in the same launch. r13-exact (best measured:
// 45.0us total).
// Failed alternatives (all measured, do not revisit): LDS W-staging r5
// +10us / r8 +3.4us; split-N waves r10 +5us (duplicated A-stream);
// single-address atomicMax r4 +30us; st-stream r6 +5us; NT row loads r12
// +9.3us; slice-phasing r9 +20us; segsum 32-waves/CU r14 +0.9us.
//
// MFMA fragment layouts (mfma_f32_16x16x32_f16, harness-verified round 1):
//   A (16x32): row = lane&15, k = (lane>>4)*8 + i  -> 8 contiguous floats
//   B (32x16): col = lane&15, k = (lane>>4)*8 + i  -> stride-DIM scalars
//   D (16x16): col = lane&15, row = (lane>>4)*4 + reg
__global__ __launch_bounds__(256, 2) void prep_kernel(
    const int* __restrict__ segs, int* __restrict__ seg_start,
    const float* __restrict__ emb, const float* __restrict__ W,
    signed char* __restrict__ qtab, float* __restrict__ scales16,
    int T, int B, int V, int mtiles, int nTrans) {
  if ((int)blockIdx.x >= nTrans) {
    // ---- boundaries: seg_start[s] = lower_bound(segs, s), streaming ----
    const int i = (blockIdx.x - nTrans) * 256 + threadIdx.x;
    if (i > T) return;
    const int cur = (i < T) ? segs[i] : B;
    const int prev = (i > 0) ? segs[i - 1] : -1;
    for (int s = prev + 1; s <= cur; ++s) seg_start[s] = i;
    return;
  }

  const int wid = blockIdx.x * 4 + (threadIdx.x >> 6);
  const int nwaves = nTrans * 4;
  const int lane = threadIdx.x & 63;
  const int lr = lane & 15;   // A-row / B-col / D-col
  const int lg = lane >> 4;   // k-group (A/B), row-group (D)

  // Preload all B fragments of W (fp32 -> fp16). W is 64KB, L1/L2-hot.
  f16x8 bfrag[8][4];
#pragma unroll
  for (int n = 0; n < 8; ++n)
#pragma unroll
    for (int s = 0; s < 4; ++s) {
      const float* wp = W + (size_t)(s * 32 + lg * 8) * DIM + n * 16 + lr;
      f16x8 f;
#pragma unroll
      for (int i = 0; i < 8; ++i) f[i] = (_Float16)wp[(size_t)i * DIM];
      bfrag[n][s] = f;
    }

  for (int mt = wid; mt < mtiles; mt += nwaves) {
    const float* arow = emb + (size_t)(mt * 16 + lr) * DIM;
    f16x8 afrag[4];
#pragma unroll
    for (int s = 0; s < 4; ++s) {
      const float4 a0 = *reinterpret_cast<const float4*>(arow + s * 32 + lg * 8);
      const float4 a1 = *reinterpret_cast<const float4*>(arow + s * 32 + lg * 8 + 4);
      f16x8 f;
      f[0] = (_Float16)a0.x; f[1] = (_Float16)a0.y;
      f[2] = (_Float16)a0.z; f[3] = (_Float16)a0.w;
      f[4] = (_Float16)a1.x; f[5] = (_Float16)a1.y;
      f[6] = (_Float16)a1.z; f[7] = (_Float16)a1.w;
      afrag[s] = f;
    }
    f32x4 accs[8];
#pragma unroll
    for (int n = 0; n < 8; ++n) {
      f32x4 a = {0.f, 0.f, 0.f, 0.f};
#pragma unroll
      for (int s = 0; s < 4; ++s)
        a = __builtin_amdgcn_mfma_f32_16x16x32_f16(afrag[s], bfrag[n][s],
                                                   a, 0, 0, 0);
      accs[n] = a;
    }
    // tile absmax: in-lane over n and j, then across all 64 lanes
    const int r0 = mt * 16 + lg * 4;
    float tm = 0.f;
#pragma unroll
    for (int j = 0; j < 4; ++j) {
      float m = fabsf(accs[0][j]);
#pragma unroll
      for (int n = 1; n < 8; ++n) m = fmaxf(m, fabsf(accs[n][j]));
      tm = fmaxf(tm, m);
    }
    tm = fmaxf(tm, __shfl_xor(tm, 1));
    tm = fmaxf(tm, __shfl_xor(tm, 2));
    tm = fmaxf(tm, __shfl_xor(tm, 4));
    tm = fmaxf(tm, __shfl_xor(tm, 8));
    tm = fmaxf(tm, __shfl_xor(tm, 16));
    tm = fmaxf(tm, __shfl_xor(tm, 32));
    const float inv = (tm > 0.f) ? 127.f / tm : 0.f;
    if (lane == 0) scales16[mt] = tm * (1.f / 127.f);
#pragma unroll
    for (int n = 0; n < 8; ++n)
#pragma unroll
      for (int j = 0; j < 4; ++j)
        qtab[(size_t)(r0 + j) * DIM + n * 16 + lr] =
            (signed char)(int)rintf(accs[n][j] * inv);
  }

  // tail rows if V % 16 != 0 (dead for V=100000, kept for safety)
  const int tailStart = mtiles * 16;
  if (wid == 0 && tailStart < V) {
    const int c2 = lane * 2;
    float tmax = 0.f;
    for (int r = tailStart; r < V; ++r) {
      float s0 = 0.f, s1 = 0.f;
      for (int k = 0; k < DIM; ++k) {
        const float e = emb[(size_t)r * DIM + k];
        s0 = fmaf(e, W[(size_t)k * DIM + c2], s0);
        s1 = fmaf(e, W[(size_t)k * DIM + c2 + 1], s1);
      }
      float mm = fmaxf(fabsf(s0), fabsf(s1));
      mm = fmaxf(mm, __shfl_xor(mm, 1));
      mm = fmaxf(mm, __shfl_xor(mm, 2));
      mm = fmaxf(mm, __shfl_xor(mm, 4));
      mm = fmaxf(mm, __shfl_xor(mm, 8));
      mm = fmaxf(mm, __shfl_xor(mm, 16));
      mm = fmaxf(mm, __shfl_xor(mm, 32));
      tmax = fmaxf(tmax, mm);
    }
    if (lane == 0) scales16[tailStart >> 4] = tmax * (1.f / 127.f);
    const float iv = (tmax > 0.f) ? 127.f / tmax : 0.f;
    for (int r = tailStart; r < V; ++r) {
      float s0 = 0.f, s1 = 0.f;
      for (int k = 0; k < DIM; ++k) {
        const float e = emb[(size_t)r * DIM + k];
        s0 = fmaf(e, W[(size_t)k * DIM + c2], s0);
        s1 = fmaf(e, W[(size_t)k * DIM + c2 + 1], s1);
      }
      qtab[(size_t)r * DIM + c2] = (signed char)(int)rintf(s0 * iv);
      qtab[(size_t)r * DIM + c2 + 1] = (signed char)(int)rintf(s1 * iv);
    }
  }
}

// ---------- Kernel 2: int8 gather + segment sum + bias + relu -------------
// r13-exact (best measured). One wave per segment (4 waves/block). 64-row
// clamped batches: 8 x dwordx4 loads in flight, each load = 8 rows (8
// lanes x 16B = one 128B row). Tile scales (25KB, L2-hot). Phase-split
// token -> scale+row -> fma; __launch_bounds__(256,4).
// segsum sits at the measured device random-request wall: 819K mandatory
// non-coalescible 128B row requests at ~29G req/s = ~28us, invariant to
// request shape (r7 vs r2), occupancy (r14: 32 waves/CU +0), NT (r12: -),
// slice-phasing (r9: -), scale granularity beyond r13's +1.8.

#define ACC4(w, o, SV)                                                     \
  acc[(o) + 0] = fmaf(SV, (float)((int)((w) << 24) >> 24), acc[(o) + 0]);  \
  acc[(o) + 1] = fmaf(SV, (float)((int)((w) << 16) >> 24), acc[(o) + 1]);  \
  acc[(o) + 2] = fmaf(SV, (float)((int)((w) <<  8) >> 24), acc[(o) + 2]);  \
  acc[(o) + 3] = fmaf(SV, (float)((int)(w) >> 24),         acc[(o) + 3]);

__global__ __launch_bounds__(256, 4) void segsum_q8(
    const int* __restrict__ tokens, const signed char* __restrict__ qtab,
    const float* __restrict__ scales16, const int* __restrict__ seg_start,
    const float* __restrict__ bias, float* __restrict__ out, int B) {
  const int seg = blockIdx.x * 4 + (threadIdx.x >> 6);
  if (seg >= B) return;
  const int lane = threadIdx.x & 63;
  const int g = lane >> 3;            // row-in-octet 0..7
  const int c16 = (lane & 7) * 16;    // byte offset of this lane's 16 dims
  const int lo = seg_start[seg], hi = seg_start[seg + 1];
  const int cnt = hi - lo;
  const int last = hi - 1;
  float acc[16] = {0.f, 0.f, 0.f, 0.f, 0.f, 0.f, 0.f, 0.f,
                   0.f, 0.f, 0.f, 0.f, 0.f, 0.f, 0.f, 0.f};

  const int nbatch = (cnt + 63) >> 6;
  for (int b = 0; b < nbatch; ++b) {
    const int base = lo + (b << 6);
    // phase 1: token indices + token loads (streamed, L1-hot)
    int idx[8], tok[8];
#pragma unroll
    for (int u = 0; u < 8; ++u) {
      idx[u] = base + 8 * u + g;
      tok[u] = tokens[min(idx[u], last)];
    }
    // phase 2: 8 tile-scale loads (25KB, L2-hot) + 8 random 128B row loads
    float sv[8];
    uint4 rv[8];
#pragma unroll
    for (int u = 0; u < 8; ++u) {
      sv[u] = (idx[u] <= last) ? scales16[tok[u] >> 4] : 0.f;
      rv[u] = *reinterpret_cast<const uint4*>(
          qtab + (size_t)tok[u] * DIM + c16);
    }
    // phase 3: decode + accumulate (masked rows have sv=0)
#pragma unroll
    for (int u = 0; u < 8; ++u) {
      ACC4(rv[u].x, 0, sv[u])
      ACC4(rv[u].y, 4, sv[u])
      ACC4(rv[u].z, 8, sv[u])
      ACC4(rv[u].w, 12, sv[u])
    }
  }
#pragma unroll
  for (int i = 0; i < 16; ++i) {
    acc[i] += __shfl_xor(acc[i], 8);
    acc[i] += __shfl_xor(acc[i], 16);
    acc[i] += __shfl_xor(acc[i], 32);
  }
  if (g == 0) {
    const int d0 = (lane & 7) * 16;
    float* op = out + (size_t)seg * DIM + d0;
    const float* bp = bias + d0;
#pragma unroll
    for (int j = 0; j < 4; ++j) {
      const float4 bv = *reinterpret_cast<const float4*>(bp + 4 * j);
      float4 o;
      o.x = fmaxf(acc[4 * j + 0] + bv.x, 0.f);
      o.y = fmaxf(acc[4 * j + 1] + bv.y, 0.f);
      o.z = fmaxf(acc[4 * j + 2] + bv.z, 0.f);
      o.w = fmaxf(acc[4 * j + 3] + bv.w, 0.f);
      *reinterpret_cast<float4*>(op + 4 * j) = o;
    }
  }
}
#undef ACC4

// =================== fp32 fallback path (ws too small) ====================
__global__ __launch_bounds__(256) void boundaries_kernel(
    const int* __restrict__ segs, int* __restrict__ seg_start, int T, int B) {
  const int i = blockIdx.x * 256 + threadIdx.x;
  if (i > T) return;
  const int cur = (i < T) ? segs[i] : B;
  const int prev = (i > 0) ? segs[i - 1] : -1;
  for (int s = prev + 1; s <= cur; ++s) seg_start[s] = i;
}

#define LOADF(u, TIDX)                                                     \
  const int t##u = tokens[(TIDX)];                                         \
  const float4 e##u = *reinterpret_cast<const float4*>(                    \
      emb + (size_t)t##u * DIM + c4);
#define ADDF(u) { acc.x += e##u.x; acc.y += e##u.y; acc.z += e##u.z; acc.w += e##u.w; }

__global__ __launch_bounds__(256, 4) void segsum_f32(
    const int* __restrict__ tokens, const float* __restrict__ emb,
    const int* __restrict__ seg_start, float* __restrict__ bow, int B) {
  const int seg = blockIdx.x * 4 + (threadIdx.x >> 6);
  if (seg >= B) return;
  const int lane = threadIdx.x & 63;
  const int half = lane >> 5;
  const int c4 = (lane & 31) * 4;
  const int lo = seg_start[seg], hi = seg_start[seg + 1];
  const int cnt = hi - lo;
  float4 acc = make_float4(0.f, 0.f, 0.f, 0.f);

  int base = lo;
  const int nb = cnt >> 4;
  for (int b = 0; b < nb; ++b, base += 16) {
    LOADF(0, base + 0 + half)  LOADF(1, base + 2 + half)
    LOADF(2, base + 4 + half)  LOADF(3, base + 6 + half)
    LOADF(4, base + 8 + half)  LOADF(5, base + 10 + half)
    LOADF(6, base + 12 + half) LOADF(7, base + 14 + half)
    ADDF(0) ADDF(1) ADDF(2) ADDF(3) ADDF(4) ADDF(5) ADDF(6) ADDF(7)
  }
  if (cnt & 15) {
    const int last = hi - 1;
#define LOADT(u) const int i##u = base + 2 * u + half; LOADF(u, min(i##u, last))
    LOADT(0) LOADT(1) LOADT(2) LOADT(3)
    LOADT(4) LOADT(5) LOADT(6) LOADT(7)
    if (i0 <= last) ADDF(0)
    if (i1 <= last) ADDF(1)
    if (i2 <= last) ADDF(2)
    if (i3 <= last) ADDF(3)
    if (i4 <= last) ADDF(4)
    if (i5 <= last) ADDF(5)
    if (i6 <= last) ADDF(6)
    if (i7 <= last) ADDF(7)
#undef LOADT
  }
  acc.x += __shfl_xor(acc.x, 32);
  acc.y += __shfl_xor(acc.y, 32);
  acc.z += __shfl_xor(acc.z, 32);
  acc.w += __shfl_xor(acc.w, 32);
  if (half == 0)
    *reinterpret_cast<float4*>(bow + (size_t)seg * DIM + c4) = acc;
}

// out = relu(bow @ W + b), in-place over d_out (fallback only)
__global__ __launch_bounds__(256) void gemm_bias_relu(
    const float* __restrict__ bow, const float* __restrict__ W,
    const float* __restrict__ bias, float* __restrict__ out) {
  __shared__ float bt[GROWS][DIM];
  const int tid = threadIdx.x;
  const size_t row0 = (size_t)blockIdx.x * GROWS;

  {
    const float4* src = reinterpret_cast<const float4*>(bow + row0 * DIM);
    float4* dst = reinterpret_cast<float4*>(&bt[0][0]);
#pragma unroll
    for (int i = 0; i < (GROWS * DIM / 4) / 256; ++i)
      dst[tid + 256 * i] = src[tid + 256 * i];
  }
  __syncthreads();

  const int cg = tid & 31;
  const int rg = tid >> 5;
  const int c0 = cg * 4;

  float acc[4][4] = {};
#pragma unroll 4
  for (int k = 0; k < DIM; ++k) {
    const float4 w4 = *reinterpret_cast<const float4*>(W + (size_t)k * DIM + c0);
#pragma unroll
    for (int j = 0; j < 4; ++j) {
      const float s = bt[rg * 4 + j][k];
      acc[j][0] = fmaf(s, w4.x, acc[j][0]);
      acc[j][1] = fmaf(s, w4.y, acc[j][1]);
      acc[j][2] = fmaf(s, w4.z, acc[j][2]);
      acc[j][3] = fmaf(s, w4.w, acc[j][3]);
    }
  }

  const float4 bv = *reinterpret_cast<const float4*>(bias + c0);
#pragma unroll
  for (int j = 0; j < 4; ++j) {
    float4 o;
    o.x = fmaxf(acc[j][0] + bv.x, 0.f);
    o.y = fmaxf(acc[j][1] + bv.y, 0.f);
    o.z = fmaxf(acc[j][2] + bv.z, 0.f);
    o.w = fmaxf(acc[j][3] + bv.w, 0.f);
    *reinterpret_cast<float4*>(out + (row0 + rg * 4 + j) * DIM + c0) = o;
  }
}

extern "C" void kernel_launch(void* const* d_in, const int* in_sizes, int n_in,
                              void* d_out, int out_size, void* d_ws, size_t ws_size,
                              hipStream_t stream) {
  const int* tokens = (const int*)d_in[0];
  const int* segs = (const int*)d_in[1];
  const float* emb = (const float*)d_in[2];
  const float* W = (const float*)d_in[3];
  const float* bias = (const float*)d_in[4];
  float* out = (float*)d_out;

  const int T = in_sizes[0];
  const int B = out_size / DIM;       // 16384
  const int V = in_sizes[2] / DIM;    // 100000

  int* seg_start = (int*)d_ws;                       // (B+1) ints
  const size_t ss_bytes = ((size_t)(B + 1) * 4 + 255) & ~(size_t)255;
  const size_t sc_bytes = (((size_t)(V + 15) / 16) * 4 + 255) & ~(size_t)255;

  const bool qok = ws_size >= ss_bytes + sc_bytes + (size_t)V * DIM;
  if (qok) {
    float* scales16 = (float*)((char*)d_ws + ss_bytes);
    signed char* qtab = (signed char*)((char*)d_ws + ss_bytes + sc_bytes);
    const int nbBound = (T + 1 + 255) / 256;
    const int NTRANS = 512;                          // 2 blocks/CU, 1 generation
    const int mtiles = V / 16;
    prep_kernel<<<NTRANS + nbBound, 256, 0, stream>>>(
        segs, seg_start, emb, W, qtab, scales16, T, B, V, mtiles, NTRANS);
    segsum_q8<<<(B + 3) / 4, 256, 0, stream>>>(
        tokens, qtab, scales16, seg_start, bias, out, B);
  } else {
    float* bow = out;                                // in-place: gather -> GEMM
    boundaries_kernel<<<(T + 1 + 255) / 256, 256, 0, stream>>>(segs, seg_start, T, B);
    segsum_f32<<<(B + 3) / 4, 256, 0, stream>>>(tokens, emb, seg_start, bow, B);
    gemm_bias_relu<<<B / GROWS, 256, 0, stream>>>(bow, W, bias, out);
  }
}